// Round 2
// baseline (2759.034 us; speedup 1.0000x reference)
//
#include <hip/hip_runtime.h>
#include <hip/hip_bf16.h>

typedef __attribute__((ext_vector_type(8))) short short8;
typedef __attribute__((ext_vector_type(4))) float f32x4;

#define EPS 1e-5f

__device__ inline unsigned short bf16_rne(float x) {
    unsigned u = __float_as_uint(x);
    unsigned r = u + 0x7FFFu + ((u >> 16) & 1u);
    return (unsigned short)(r >> 16);
}

__device__ inline float sigmoidf_fast(float x) {
    return 1.0f / (1.0f + __expf(-x));
}

__device__ inline float tanhf_fast(float x) {
    float ax = fabsf(x);
    float e = __expf(-2.0f * ax);
    float t = (1.0f - e) / (1.0f + e);
    return copysignf(t, x);
}

// ---------------------------------------------------------------------------
// prep: W1 (K=256 x N=256 f32, row-major [k][n]) -> W_T hi/lo bf16 [n][k]
// ---------------------------------------------------------------------------
__global__ void prep_w(const float* __restrict__ W1,
                       short* __restrict__ WhiT, short* __restrict__ WloT) {
    int n = blockIdx.x;   // 0..255
    int k = threadIdx.x;  // 0..255
    float x = W1[k * 256 + n];
    unsigned short hi = bf16_rne(x);
    float fh = __uint_as_float(((unsigned)hi) << 16);
    unsigned short lo = bf16_rne(x - fh);
    WhiT[n * 256 + k] = (short)hi;
    WloT[n * 256 + k] = (short)lo;
}

// ---------------------------------------------------------------------------
// gemm_stats: h[e][0:256] = concat(node_emb[i[e]], edge_emb[e]) @ W1 + b1
// split-bf16 (3-MFMA: AhBh + AhBl + AlBh) for ~fp32 precision. Also
// accumulates per-column sum/sumsq for BN1 (one atomicAdd per col per wave).
// Block: 256 thr = 4 waves; tile 64 rows x 256 cols; wave w -> cols [64w,64w+64)
// ---------------------------------------------------------------------------
__global__ __launch_bounds__(256) void gemm_stats(
    const float* __restrict__ node_emb, const float* __restrict__ edge_emb,
    const int* __restrict__ idx,
    const short* __restrict__ WhiT, const short* __restrict__ WloT,
    const float* __restrict__ b1, float* __restrict__ h,
    float* __restrict__ sum1, float* __restrict__ sumsq1) {
    // row stride 40 halfs (80B): lanes r and r+8 alias banks -> 2-way (free)
    __shared__ __align__(16) short Ahi[64][40];
    __shared__ __align__(16) short Alo[64][40];

    const int tid = threadIdx.x;
    const int row0 = blockIdx.x * 64;
    const int sr = tid >> 2;  // staging row 0..63
    const int sq = tid & 3;   // staging k-quad (8 floats each)
    const size_t e = (size_t)row0 + sr;
    const float* nodeptr = node_emb + (size_t)idx[e] * 128;
    const float* edgeptr = edge_emb + e * 128;

    const int lane = tid & 63;
    const int wid = tid >> 6;
    const int l15 = lane & 15;
    const int lg = lane >> 4;  // 0..3

    f32x4 acc[4][4];
#pragma unroll
    for (int a = 0; a < 4; ++a)
#pragma unroll
        for (int b = 0; b < 4; ++b) acc[a][b] = (f32x4){0.f, 0.f, 0.f, 0.f};

    const short* bbase_hi = WhiT + (wid * 64 + l15) * 256 + lg * 8;
    const short* bbase_lo = WloT + (wid * 64 + l15) * 256 + lg * 8;

    for (int kk = 0; kk < 8; ++kk) {
        const int k0 = kk * 32;
        const float* src = (k0 < 128) ? (nodeptr + k0 + sq * 8)
                                      : (edgeptr + (k0 - 128) + sq * 8);
        float4 va = *(const float4*)src;
        float4 vb = *(const float4*)(src + 4);
        float vals[8] = {va.x, va.y, va.z, va.w, vb.x, vb.y, vb.z, vb.w};
        short8 vhi, vlo;
#pragma unroll
        for (int j = 0; j < 8; ++j) {
            unsigned short hb = bf16_rne(vals[j]);
            float fh = __uint_as_float(((unsigned)hb) << 16);
            unsigned short lb = bf16_rne(vals[j] - fh);
            vhi[j] = (short)hb;
            vlo[j] = (short)lb;
        }
        if (kk) __syncthreads();  // prior iter's frag reads done
        *(short8*)(&Ahi[sr][sq * 8]) = vhi;
        *(short8*)(&Alo[sr][sq * 8]) = vlo;
        __syncthreads();

        short8 af_hi[4], af_lo[4];
#pragma unroll
        for (int mt = 0; mt < 4; ++mt) {
            af_hi[mt] = *(const short8*)(&Ahi[mt * 16 + l15][lg * 8]);
            af_lo[mt] = *(const short8*)(&Alo[mt * 16 + l15][lg * 8]);
        }
#pragma unroll
        for (int nt = 0; nt < 4; ++nt) {
            short8 bh = *(const short8*)(bbase_hi + nt * 16 * 256 + k0);
            short8 bl = *(const short8*)(bbase_lo + nt * 16 * 256 + k0);
#pragma unroll
            for (int mt = 0; mt < 4; ++mt) {
                acc[mt][nt] = __builtin_amdgcn_mfma_f32_16x16x32_bf16(
                    af_hi[mt], bh, acc[mt][nt], 0, 0, 0);
                acc[mt][nt] = __builtin_amdgcn_mfma_f32_16x16x32_bf16(
                    af_hi[mt], bl, acc[mt][nt], 0, 0, 0);
                acc[mt][nt] = __builtin_amdgcn_mfma_f32_16x16x32_bf16(
                    af_lo[mt], bh, acc[mt][nt], 0, 0, 0);
            }
        }
    }

    // Epilogue: +bias, store h, per-column stats (C/D: col=l&15, row=lg*4+v)
    const int colbase = wid * 64 + l15;
#pragma unroll
    for (int nt = 0; nt < 4; ++nt) {
        const int col = colbase + nt * 16;
        const float bv = b1[col];
        float s = 0.f, q = 0.f;
#pragma unroll
        for (int mt = 0; mt < 4; ++mt) {
            const size_t rbase = (size_t)row0 + mt * 16 + lg * 4;
#pragma unroll
            for (int v = 0; v < 4; ++v) {
                float hv = acc[mt][nt][v] + bv;
                h[(rbase + v) * 256 + col] = hv;
                s += hv;
                q += hv * hv;
            }
        }
        s += __shfl_xor(s, 16);
        s += __shfl_xor(s, 32);
        q += __shfl_xor(q, 16);
        q += __shfl_xor(q, 32);
        if (lg == 0) {
            atomicAdd(&sum1[col], s);
            atomicAdd(&sumsq1[col], q);
        }
    }
}

// ---------------------------------------------------------------------------
// bn1_finalize: fold BN1 into per-column scale/shift (s1t1[0:256]=s, [256:512]=t)
// ---------------------------------------------------------------------------
__global__ void bn1_finalize(const float* __restrict__ sum1,
                             const float* __restrict__ sumsq1,
                             const float* __restrict__ gamma1,
                             const float* __restrict__ beta1,
                             float* __restrict__ s1t1, int E) {
    int c = threadIdx.x;
    float invE = 1.0f / (float)E;
    float mu = sum1[c] * invE;
    float var = sumsq1[c] * invE - mu * mu;
    float s = gamma1[c] * rsqrtf(var + EPS);
    s1t1[c] = s;
    s1t1[256 + c] = beta1[c] - mu * s;
}

// ---------------------------------------------------------------------------
// gate_scatter: msg = sigmoid(BN(h_f)) * tanh(BN(h_c)); atomicAdd into agg
// 32 threads per edge, 4 cols per thread (float4)
// ---------------------------------------------------------------------------
__global__ __launch_bounds__(256) void gate_scatter(
    const float* __restrict__ h, const int* __restrict__ idx,
    const float* __restrict__ s1t1, float* __restrict__ agg) {
    const int t = threadIdx.x;
    const size_t e = (size_t)blockIdx.x * 8 + (t >> 5);
    const int c = (t & 31) * 4;
    const int n = idx[e];
    const float4 hf = *(const float4*)(h + e * 256 + c);
    const float4 hc = *(const float4*)(h + e * 256 + 128 + c);
    const float4 sf = *(const float4*)(s1t1 + c);
    const float4 tf = *(const float4*)(s1t1 + 256 + c);
    const float4 sc = *(const float4*)(s1t1 + 128 + c);
    const float4 tc = *(const float4*)(s1t1 + 256 + 128 + c);
    float zf, zc, m;
    float* dst = agg + (size_t)n * 128 + c;
    zf = hf.x * sf.x + tf.x; zc = hc.x * sc.x + tc.x;
    m = sigmoidf_fast(zf) * tanhf_fast(zc); atomicAdd(dst + 0, m);
    zf = hf.y * sf.y + tf.y; zc = hc.y * sc.y + tc.y;
    m = sigmoidf_fast(zf) * tanhf_fast(zc); atomicAdd(dst + 1, m);
    zf = hf.z * sf.z + tf.z; zc = hc.z * sc.z + tc.z;
    m = sigmoidf_fast(zf) * tanhf_fast(zc); atomicAdd(dst + 2, m);
    zf = hf.w * sf.w + tf.w; zc = hc.w * sc.w + tc.w;
    m = sigmoidf_fast(zf) * tanhf_fast(zc); atomicAdd(dst + 3, m);
}

// ---------------------------------------------------------------------------
// bn2_stats: column sums over agg (N x 128)
// ---------------------------------------------------------------------------
__global__ void bn2_stats(const float* __restrict__ agg, float* __restrict__ sum2,
                          float* __restrict__ sumsq2, int N) {
    const int gt = blockIdx.x * blockDim.x + threadIdx.x;
    const int c = (gt & 31) * 4;
    int r = gt >> 5;
    const int rstride = (gridDim.x * blockDim.x) >> 5;
    float s0 = 0, s1 = 0, s2 = 0, s3 = 0, q0 = 0, q1 = 0, q2 = 0, q3 = 0;
    for (; r < N; r += rstride) {
        float4 a = *(const float4*)(agg + (size_t)r * 128 + c);
        s0 += a.x; s1 += a.y; s2 += a.z; s3 += a.w;
        q0 += a.x * a.x; q1 += a.y * a.y; q2 += a.z * a.z; q3 += a.w * a.w;
    }
    atomicAdd(&sum2[c + 0], s0); atomicAdd(&sum2[c + 1], s1);
    atomicAdd(&sum2[c + 2], s2); atomicAdd(&sum2[c + 3], s3);
    atomicAdd(&sumsq2[c + 0], q0); atomicAdd(&sumsq2[c + 1], q1);
    atomicAdd(&sumsq2[c + 2], q2); atomicAdd(&sumsq2[c + 3], q3);
}

// ---------------------------------------------------------------------------
// finalize: out = tanh(node_emb + BN2(agg))
// ---------------------------------------------------------------------------
__global__ void finalize(const float* __restrict__ node,
                         const float* __restrict__ agg,
                         const float* __restrict__ sum2,
                         const float* __restrict__ sumsq2,
                         const float* __restrict__ gamma2,
                         const float* __restrict__ beta2,
                         float* __restrict__ out, int N) {
    const size_t gt = (size_t)blockIdx.x * blockDim.x + threadIdx.x;
    const size_t base = gt * 4;
    if (base >= (size_t)N * 128) return;
    const int c = (int)(base & 127);
    const float invN = 1.0f / (float)N;
    float4 a = *(const float4*)(agg + base);
    float4 x = *(const float4*)(node + base);
    float av[4] = {a.x, a.y, a.z, a.w};
    float xv[4] = {x.x, x.y, x.z, x.w};
    float4 o;
    float ov[4];
#pragma unroll
    for (int j = 0; j < 4; ++j) {
        float mu = sum2[c + j] * invN;
        float var = sumsq2[c + j] * invN - mu * mu;
        float s = gamma2[c + j] * rsqrtf(var + EPS);
        float t = beta2[c + j] - mu * s;
        ov[j] = tanhf_fast(xv[j] + av[j] * s + t);
    }
    o.x = ov[0]; o.y = ov[1]; o.z = ov[2]; o.w = ov[3];
    *(float4*)(out + base) = o;
}

// ---------------------------------------------------------------------------
extern "C" void kernel_launch(void* const* d_in, const int* in_sizes, int n_in,
                              void* d_out, int out_size, void* d_ws, size_t ws_size,
                              hipStream_t stream) {
    const float* node_emb = (const float*)d_in[0];
    const float* edge_emb = (const float*)d_in[1];
    const int* idx = (const int*)d_in[2];
    const float* W1 = (const float*)d_in[3];
    const float* b1 = (const float*)d_in[4];
    const float* gamma1 = (const float*)d_in[5];
    const float* beta1 = (const float*)d_in[6];
    const float* gamma2 = (const float*)d_in[7];
    const float* beta2 = (const float*)d_in[8];
    float* out = (float*)d_out;

    const int E = in_sizes[2];       // 800000
    const int N = in_sizes[0] / 128; // 50000

    // workspace layout
    char* ws = (char*)d_ws;
    float* h = (float*)ws;                                     // E*256 f32
    float* agg = (float*)(ws + (size_t)E * 256 * 4);           // N*128 f32
    float* stats = (float*)(ws + (size_t)E * 256 * 4 + (size_t)N * 128 * 4);
    float* sum1 = stats;          // 256
    float* sumsq1 = sum1 + 256;   // 256
    float* s1t1 = sumsq1 + 256;   // 512
    float* sum2 = s1t1 + 512;     // 128
    float* sumsq2 = sum2 + 128;   // 128
    short* WhiT = (short*)(sumsq2 + 128);  // 65536 bf16
    short* WloT = WhiT + 65536;            // 65536 bf16

    // zero agg + all stat accumulators (one contiguous region)
    hipMemsetAsync(agg, 0, (size_t)N * 128 * 4 + 1280 * 4, stream);

    prep_w<<<256, 256, 0, stream>>>(W1, WhiT, WloT);
    gemm_stats<<<E / 64, 256, 0, stream>>>(node_emb, edge_emb, idx, WhiT, WloT,
                                           b1, h, sum1, sumsq1);
    bn1_finalize<<<1, 256, 0, stream>>>(sum1, sumsq1, gamma1, beta1, s1t1, E);
    gate_scatter<<<E / 8, 256, 0, stream>>>(h, idx, s1t1, agg);
    bn2_stats<<<256, 256, 0, stream>>>(agg, sum2, sumsq2, N);
    finalize<<<(int)(((size_t)N * 128 / 4 + 255) / 256), 256, 0, stream>>>(
        node_emb, agg, sum2, sumsq2, gamma2, beta2, out, N);
}

// Round 4
// 1726.892 us; speedup vs baseline: 1.5977x; 1.5977x over previous
//
#include <hip/hip_runtime.h>
#include <hip/hip_bf16.h>

typedef __attribute__((ext_vector_type(8))) short short8;
typedef __attribute__((ext_vector_type(4))) float f32x4;

#define EPS 1e-5f

__device__ inline unsigned short bf16_rne(float x) {
    unsigned u = __float_as_uint(x);
    unsigned r = u + 0x7FFFu + ((u >> 16) & 1u);
    return (unsigned short)(r >> 16);
}

__device__ inline float sigmoidf_fast(float x) {
    return 1.0f / (1.0f + __expf(-x));
}

__device__ inline float tanhf_fast(float x) {
    float ax = fabsf(x);
    float e = __expf(-2.0f * ax);
    float t = (1.0f - e) / (1.0f + e);
    return copysignf(t, x);
}

// ---------------------------------------------------------------------------
// prep: W1 (K=256 x N=256 f32, row-major [k][n]) -> W_T hi/lo bf16 [n][k]
// ---------------------------------------------------------------------------
__global__ void prep_w(const float* __restrict__ W1,
                       short* __restrict__ WhiT, short* __restrict__ WloT) {
    int n = blockIdx.x;   // 0..255
    int k = threadIdx.x;  // 0..255
    float x = W1[k * 256 + n];
    unsigned short hi = bf16_rne(x);
    float fh = __uint_as_float(((unsigned)hi) << 16);
    unsigned short lo = bf16_rne(x - fh);
    WhiT[n * 256 + k] = (short)hi;
    WloT[n * 256 + k] = (short)lo;
}

// ---------------------------------------------------------------------------
// gemm_stats v2: 2-phase full-half-K staging (phase0 = node K 0..127,
// phase1 = edge K 128..255). XOR-swizzled LDS (chunk^(row&7)) -> no bank
// conflicts, no padding. 3 barriers per block total (vs 16 in v1).
// Block: 256 thr = 4 waves; tile 64 rows x 256 cols; wave w -> cols [64w,64w+64)
// ---------------------------------------------------------------------------
__global__ __launch_bounds__(256) void gemm_stats(
    const float* __restrict__ node_emb, const float* __restrict__ edge_emb,
    const int* __restrict__ idx,
    const short* __restrict__ WhiT, const short* __restrict__ WloT,
    const float* __restrict__ b1, float* __restrict__ h,
    float* __restrict__ sum1, float* __restrict__ sumsq1) {
    __shared__ __align__(16) short Ahi[64 * 128];  // 16 KB, swizzled chunks
    __shared__ __align__(16) short Alo[64 * 128];  // 16 KB

    const int tid = threadIdx.x;
    const int row0 = blockIdx.x * 64;
    const int r = tid >> 2;   // staging row 0..63
    const int q = tid & 3;    // staging quarter (4 chunks of 8 elems)
    const size_t e = (size_t)row0 + r;
    const float* nodeptr = node_emb + (size_t)idx[e] * 128;
    const float* edgeptr = edge_emb + e * 128;

    const int lane = tid & 63;
    const int wid = tid >> 6;
    const int l15 = lane & 15;
    const int lg = lane >> 4;  // 0..3

    f32x4 acc[4][4];
#pragma unroll
    for (int a = 0; a < 4; ++a)
#pragma unroll
        for (int b = 0; b < 4; ++b) acc[a][b] = (f32x4){0.f, 0.f, 0.f, 0.f};

    const short* bbase_hi = WhiT + (wid * 64 + l15) * 256 + lg * 8;
    const short* bbase_lo = WloT + (wid * 64 + l15) * 256 + lg * 8;

#pragma unroll
    for (int ph = 0; ph < 2; ++ph) {
        const float* src = ph ? edgeptr : nodeptr;
        if (ph) __syncthreads();  // phase-0 fragment reads done before restage
#pragma unroll
        for (int cc = 0; cc < 4; ++cc) {
            const int c = q * 4 + cc;  // chunk 0..15 (8 bf16 each)
            const int k0 = c * 8;
            float4 va = *(const float4*)(src + k0);
            float4 vb = *(const float4*)(src + k0 + 4);
            float vals[8] = {va.x, va.y, va.z, va.w, vb.x, vb.y, vb.z, vb.w};
            short8 vhi, vlo;
#pragma unroll
            for (int j = 0; j < 8; ++j) {
                unsigned short hb = bf16_rne(vals[j]);
                float fh = __uint_as_float(((unsigned)hb) << 16);
                unsigned short lb = bf16_rne(vals[j] - fh);
                vhi[j] = (short)hb;
                vlo[j] = (short)lb;
            }
            const int off = r * 128 + (c ^ (r & 7)) * 8;
            *(short8*)(Ahi + off) = vhi;
            *(short8*)(Alo + off) = vlo;
        }
        __syncthreads();

#pragma unroll
        for (int ks = 0; ks < 4; ++ks) {
            short8 ah[4], al[4];
#pragma unroll
            for (int mt = 0; mt < 4; ++mt) {
                const int row = mt * 16 + l15;
                const int off = row * 128 + ((ks * 4 + lg) ^ (row & 7)) * 8;
                ah[mt] = *(const short8*)(Ahi + off);
                al[mt] = *(const short8*)(Alo + off);
            }
            const int kglob = ph * 128 + ks * 32;
#pragma unroll
            for (int nt = 0; nt < 4; ++nt) {
                short8 bh = *(const short8*)(bbase_hi + nt * 16 * 256 + kglob);
                short8 bl = *(const short8*)(bbase_lo + nt * 16 * 256 + kglob);
#pragma unroll
                for (int mt = 0; mt < 4; ++mt) {
                    acc[mt][nt] = __builtin_amdgcn_mfma_f32_16x16x32_bf16(
                        ah[mt], bh, acc[mt][nt], 0, 0, 0);
                    acc[mt][nt] = __builtin_amdgcn_mfma_f32_16x16x32_bf16(
                        ah[mt], bl, acc[mt][nt], 0, 0, 0);
                    acc[mt][nt] = __builtin_amdgcn_mfma_f32_16x16x32_bf16(
                        al[mt], bh, acc[mt][nt], 0, 0, 0);
                }
            }
        }
    }

    // Epilogue: +bias, store h, per-column stats (C/D: col=l&15, row=lg*4+v)
    const int colbase = wid * 64 + l15;
#pragma unroll
    for (int nt = 0; nt < 4; ++nt) {
        const int col = colbase + nt * 16;
        const float bv = b1[col];
        float s = 0.f, qq = 0.f;
#pragma unroll
        for (int mt = 0; mt < 4; ++mt) {
            const size_t rbase = (size_t)row0 + mt * 16 + lg * 4;
#pragma unroll
            for (int v = 0; v < 4; ++v) {
                float hv = acc[mt][nt][v] + bv;
                h[(rbase + v) * 256 + col] = hv;
                s += hv;
                qq += hv * hv;
            }
        }
        s += __shfl_xor(s, 16);
        s += __shfl_xor(s, 32);
        qq += __shfl_xor(qq, 16);
        qq += __shfl_xor(qq, 32);
        if (lg == 0) {
            atomicAdd(&sum1[col], s);
            atomicAdd(&sumsq1[col], qq);
        }
    }
}

// ---------------------------------------------------------------------------
// bn1_finalize: fold BN1 into per-column scale/shift (s1t1[0:256]=s, [256:512]=t)
// ---------------------------------------------------------------------------
__global__ void bn1_finalize(const float* __restrict__ sum1,
                             const float* __restrict__ sumsq1,
                             const float* __restrict__ gamma1,
                             const float* __restrict__ beta1,
                             float* __restrict__ s1t1, int E) {
    int c = threadIdx.x;
    float invE = 1.0f / (float)E;
    float mu = sum1[c] * invE;
    float var = sumsq1[c] * invE - mu * mu;
    float s = gamma1[c] * rsqrtf(var + EPS);
    s1t1[c] = s;
    s1t1[256 + c] = beta1[c] - mu * s;
}

// ---------------------------------------------------------------------------
// CSR build: hist -> scan -> fill
// ---------------------------------------------------------------------------
__global__ void csr_hist(const int* __restrict__ idx, int* __restrict__ cnt,
                         int E) {
    int e = blockIdx.x * 256 + threadIdx.x;
    if (e < E) atomicAdd(&cnt[idx[e]], 1);
}

__global__ __launch_bounds__(1024) void csr_scan(const int* __restrict__ cnt,
                                                 int* __restrict__ offs, int N) {
    __shared__ int part[1024];
    const int t = threadIdx.x;
    const int CH = (N + 1023) / 1024;
    const int base = t * CH;
    int s = 0;
    for (int i = 0; i < CH; ++i)
        if (base + i < N) s += cnt[base + i];
    part[t] = s;
    __syncthreads();
    for (int d = 1; d < 1024; d <<= 1) {
        int v = (t >= d) ? part[t - d] : 0;
        __syncthreads();
        part[t] += v;
        __syncthreads();
    }
    int run = (t ? part[t - 1] : 0);
    for (int i = 0; i < CH; ++i) {
        int g = base + i;
        if (g < N) {
            offs[g] = run;
            run += cnt[g];
        }
    }
    if (t == 1023) offs[N] = run;
}

__global__ void csr_fill(const int* __restrict__ idx,
                         const int* __restrict__ offs, int* __restrict__ cursor,
                         int* __restrict__ elist, int E) {
    int e = blockIdx.x * 256 + threadIdx.x;
    if (e < E) {
        int n = idx[e];
        int p = atomicAdd(&cursor[n], 1);
        elist[offs[n] + p] = e;
    }
}

// ---------------------------------------------------------------------------
// gate_gather: per node, sum over its edges of sigmoid(BN(h_f))*tanh(BN(h_c));
// plain store to agg (NO atomics). 32 lanes per node, 4 cols per lane.
// ---------------------------------------------------------------------------
__global__ __launch_bounds__(256) void gate_gather(
    const float* __restrict__ h, const int* __restrict__ offs,
    const int* __restrict__ elist, const float* __restrict__ s1t1,
    float* __restrict__ agg, int N) {
    const int t = threadIdx.x;
    const int n = blockIdx.x * 8 + (t >> 5);
    const int c = (t & 31) * 4;
    const float4 sf = *(const float4*)(s1t1 + c);
    const float4 tf = *(const float4*)(s1t1 + 256 + c);
    const float4 sc = *(const float4*)(s1t1 + 128 + c);
    const float4 tc = *(const float4*)(s1t1 + 384 + c);
    const int j0 = offs[n];
    const int j1 = offs[n + 1];
    float a0 = 0.f, a1 = 0.f, a2 = 0.f, a3 = 0.f;
    for (int j = j0; j < j1; ++j) {
        const size_t e = (size_t)elist[j];
        const float4 hf = *(const float4*)(h + e * 256 + c);
        const float4 hc = *(const float4*)(h + e * 256 + 128 + c);
        a0 += sigmoidf_fast(hf.x * sf.x + tf.x) * tanhf_fast(hc.x * sc.x + tc.x);
        a1 += sigmoidf_fast(hf.y * sf.y + tf.y) * tanhf_fast(hc.y * sc.y + tc.y);
        a2 += sigmoidf_fast(hf.z * sf.z + tf.z) * tanhf_fast(hc.z * sc.z + tc.z);
        a3 += sigmoidf_fast(hf.w * sf.w + tf.w) * tanhf_fast(hc.w * sc.w + tc.w);
    }
    *(float4*)(agg + (size_t)n * 128 + c) = make_float4(a0, a1, a2, a3);
}

// ---------------------------------------------------------------------------
// bn2_stats: column sums over agg (N x 128)
// ---------------------------------------------------------------------------
__global__ void bn2_stats(const float* __restrict__ agg, float* __restrict__ sum2,
                          float* __restrict__ sumsq2, int N) {
    const int gt = blockIdx.x * blockDim.x + threadIdx.x;
    const int c = (gt & 31) * 4;
    int r = gt >> 5;
    const int rstride = (gridDim.x * blockDim.x) >> 5;
    float s0 = 0, s1 = 0, s2 = 0, s3 = 0, q0 = 0, q1 = 0, q2 = 0, q3 = 0;
    for (; r < N; r += rstride) {
        float4 a = *(const float4*)(agg + (size_t)r * 128 + c);
        s0 += a.x; s1 += a.y; s2 += a.z; s3 += a.w;
        q0 += a.x * a.x; q1 += a.y * a.y; q2 += a.z * a.z; q3 += a.w * a.w;
    }
    atomicAdd(&sum2[c + 0], s0); atomicAdd(&sum2[c + 1], s1);
    atomicAdd(&sum2[c + 2], s2); atomicAdd(&sum2[c + 3], s3);
    atomicAdd(&sumsq2[c + 0], q0); atomicAdd(&sumsq2[c + 1], q1);
    atomicAdd(&sumsq2[c + 2], q2); atomicAdd(&sumsq2[c + 3], q3);
}

// ---------------------------------------------------------------------------
// finalize: out = tanh(node_emb + BN2(agg))
// ---------------------------------------------------------------------------
__global__ void finalize(const float* __restrict__ node,
                         const float* __restrict__ agg,
                         const float* __restrict__ sum2,
                         const float* __restrict__ sumsq2,
                         const float* __restrict__ gamma2,
                         const float* __restrict__ beta2,
                         float* __restrict__ out, int N) {
    const size_t gt = (size_t)blockIdx.x * blockDim.x + threadIdx.x;
    const size_t base = gt * 4;
    if (base >= (size_t)N * 128) return;
    const int c = (int)(base & 127);
    const float invN = 1.0f / (float)N;
    float4 a = *(const float4*)(agg + base);
    float4 x = *(const float4*)(node + base);
    float av[4] = {a.x, a.y, a.z, a.w};
    float xv[4] = {x.x, x.y, x.z, x.w};
    float4 o;
    float ov[4];
#pragma unroll
    for (int j = 0; j < 4; ++j) {
        float mu = sum2[c + j] * invN;
        float var = sumsq2[c + j] * invN - mu * mu;
        float s = gamma2[c + j] * rsqrtf(var + EPS);
        float t = beta2[c + j] - mu * s;
        ov[j] = tanhf_fast(xv[j] + av[j] * s + t);
    }
    o.x = ov[0]; o.y = ov[1]; o.z = ov[2]; o.w = ov[3];
    *(float4*)(out + base) = o;
}

// ---------------------------------------------------------------------------
extern "C" void kernel_launch(void* const* d_in, const int* in_sizes, int n_in,
                              void* d_out, int out_size, void* d_ws, size_t ws_size,
                              hipStream_t stream) {
    const float* node_emb = (const float*)d_in[0];
    const float* edge_emb = (const float*)d_in[1];
    const int* idx = (const int*)d_in[2];
    const float* W1 = (const float*)d_in[3];
    const float* b1 = (const float*)d_in[4];
    const float* gamma1 = (const float*)d_in[5];
    const float* beta1 = (const float*)d_in[6];
    const float* gamma2 = (const float*)d_in[7];
    const float* beta2 = (const float*)d_in[8];
    float* out = (float*)d_out;

    const int E = in_sizes[2];       // 800000
    const int N = in_sizes[0] / 128; // 50000

    // workspace layout
    float* h = (float*)d_ws;                 // E*256
    float* agg = h + (size_t)E * 256;        // N*128
    float* zbase = agg + (size_t)N * 128;    // ---- zeroed region start ----
    float* sum1 = zbase;                     // 256
    float* sumsq1 = sum1 + 256;              // 256
    float* s1t1 = sumsq1 + 256;              // 512
    float* sum2 = s1t1 + 512;                // 128
    float* sumsq2 = sum2 + 128;              // 128
    int* cnt = (int*)(sumsq2 + 128);         // N
    int* cursor = cnt + N;                   // N   ---- zeroed region end ----
    int* offs = cursor + N;                  // N+8 (pad keeps W 16B-aligned)
    int* elist = offs + N + 8;               // E
    short* WhiT = (short*)(elist + E);       // 65536 bf16
    short* WloT = WhiT + 65536;              // 65536 bf16

    const size_t zero_bytes = (size_t)(1280 + 2 * N) * 4;
    hipMemsetAsync(zbase, 0, zero_bytes, stream);

    prep_w<<<256, 256, 0, stream>>>(W1, WhiT, WloT);
    csr_hist<<<(E + 255) / 256, 256, 0, stream>>>(idx, cnt, E);
    csr_scan<<<1, 1024, 0, stream>>>(cnt, offs, N);
    csr_fill<<<(E + 255) / 256, 256, 0, stream>>>(idx, offs, cursor, elist, E);
    gemm_stats<<<E / 64, 256, 0, stream>>>(node_emb, edge_emb, idx, WhiT, WloT,
                                           b1, h, sum1, sumsq1);
    bn1_finalize<<<1, 256, 0, stream>>>(sum1, sumsq1, gamma1, beta1, s1t1, E);
    gate_gather<<<N / 8, 256, 0, stream>>>(h, offs, elist, s1t1, agg, N);
    bn2_stats<<<256, 256, 0, stream>>>(agg, sum2, sumsq2, N);
    finalize<<<(int)(((size_t)N * 128 / 4 + 255) / 256), 256, 0, stream>>>(
        node_emb, agg, sum2, sumsq2, gamma2, beta2, out, N);
}